// Round 6
// baseline (427.076 us; speedup 1.0000x reference)
//
#include <hip/hip_runtime.h>

#define D 32
#define GBITS 6
#define GSIZE 64               // rows per group
#define BLK 256
#define PAIRS_PER_CHUNK 1024   // pairs per hist/scatter chunk
#define IPT 4                  // PAIRS_PER_CHUNK / BLK

typedef unsigned long long ull;

static __device__ __forceinline__ unsigned short f2h(float f) {
    _Float16 h = (_Float16)f;
    return __builtin_bit_cast(unsigned short, h);
}
static __device__ __forceinline__ float h2f(unsigned short u) {
    return (float)__builtin_bit_cast(_Float16, u);
}

// ---------------------------------------------------------------------------
// K1: per-node precompute.  ab[n] = (x[n].sheafW[0:D], x[n].sheafW[D:2D])
//     y[n,:] = lin_W @ x[n] + lin_b
// ---------------------------------------------------------------------------
__global__ void k_node_pre(const float* __restrict__ x,
                           const float* __restrict__ sheafW,
                           const float* __restrict__ linW,
                           const float* __restrict__ linb,
                           float2* __restrict__ ab,
                           float* __restrict__ y, int N) {
    __shared__ float sW[D * D];
    __shared__ float sB[D];
    __shared__ float sS[2 * D];
    for (int i = threadIdx.x; i < D * D; i += blockDim.x) sW[i] = linW[i];
    if (threadIdx.x < D) sB[threadIdx.x] = linb[threadIdx.x];
    if (threadIdx.x < 2 * D) sS[threadIdx.x] = sheafW[threadIdx.x];
    __syncthreads();

    int n = blockIdx.x * blockDim.x + threadIdx.x;
    if (n >= N) return;

    float xv[D];
    const float4* xp = reinterpret_cast<const float4*>(x + (size_t)n * D);
#pragma unroll
    for (int i = 0; i < D / 4; ++i) {
        float4 v = xp[i];
        xv[4 * i + 0] = v.x; xv[4 * i + 1] = v.y;
        xv[4 * i + 2] = v.z; xv[4 * i + 3] = v.w;
    }

    float av = 0.f, bv = 0.f;
#pragma unroll
    for (int d = 0; d < D; ++d) { av += xv[d] * sS[d]; bv += xv[d] * sS[D + d]; }
    ab[n] = make_float2(av, bv);

    float4* yp = reinterpret_cast<float4*>(y + (size_t)n * D);
#pragma unroll
    for (int j4 = 0; j4 < D / 4; ++j4) {
        float4 o;
#pragma unroll
        for (int jj = 0; jj < 4; ++jj) {
            int j = 4 * j4 + jj;
            float s = sB[j];
#pragma unroll
            for (int d = 0; d < D; ++d) s += xv[d] * sW[j * D + d];
            (&o.x)[jj] = s;
        }
        yp[j4] = o;
    }
}

// ---------------------------------------------------------------------------
// K2: per undirected pair -> two packed items (row<<48|col<<32|m16|mr16)
//     fused with blocked histogram of bin = row >> GBITS.
//     Chunk c = pairs [c*PPC,(c+1)*PPC) -> items at those idx and +E2.
// ---------------------------------------------------------------------------
__global__ void k_edge_items_hist(const int* __restrict__ ei,
                                  const float2* __restrict__ ab,
                                  ull* __restrict__ items,
                                  int* __restrict__ bhist,
                                  int E2, int E, int nblkH, int NBG) {
    __shared__ int hist[1024];
    for (int i = threadIdx.x; i < NBG; i += BLK) hist[i] = 0;
    __syncthreads();
    int base = blockIdx.x * PAIRS_PER_CHUNK;
#pragma unroll
    for (int k = 0; k < IPT; ++k) {
        int i = base + k * BLK + threadIdx.x;
        if (i < E2) {
            int s = ei[i];
            int t = ei[E + i];
            float2 as = ab[s], at = ab[t];
            float m  = tanhf(as.x + at.y);
            float mr = tanhf(at.x + as.y);
            ull hm = f2h(m), hmr = f2h(mr);
            items[i]      = ((ull)(unsigned)s << 48) | ((ull)(unsigned)t << 32) | (hm << 16) | hmr;
            items[i + E2] = ((ull)(unsigned)t << 48) | ((ull)(unsigned)s << 32) | (hmr << 16) | hm;
            atomicAdd(&hist[s >> GBITS], 1);
            atomicAdd(&hist[t >> GBITS], 1);
        }
    }
    __syncthreads();
    for (int i = threadIdx.x; i < NBG; i += BLK)
        bhist[(size_t)i * nblkH + blockIdx.x] = hist[i];
}

// ---------------------------------------------------------------------------
// Scan level A: 256-elem blocks, local exclusive in place + block sums.
// ---------------------------------------------------------------------------
__global__ void k_scanA(int* __restrict__ data, int* __restrict__ bsum, int M) {
    __shared__ int s[256];
    int t = threadIdx.x;
    int i = blockIdx.x * 256 + t;
    int v = (i < M) ? data[i] : 0;
    s[t] = v;
    __syncthreads();
#pragma unroll
    for (int o = 1; o < 256; o <<= 1) {
        int tmp = (t >= o) ? s[t - o] : 0;
        __syncthreads();
        s[t] += tmp;
        __syncthreads();
    }
    if (i < M) data[i] = s[t] - v;
    if (t == 255) bsum[blockIdx.x] = s[255];
}

// ---------------------------------------------------------------------------
// Scan level B: one 1024-thread block, in-place exclusive scan of NB elems
// (each thread owns a contiguous chunk; handles NB up to 4096+).
// ---------------------------------------------------------------------------
__global__ void k_scanB(int* __restrict__ data, int NB) {
    __shared__ int s[1024];
    int t = threadIdx.x;
    int per = (NB + 1023) >> 10;
    int beg = t * per;
    int end_ = min(beg + per, NB);
    int sum = 0;
    for (int i = beg; i < end_; ++i) sum += data[i];
    s[t] = sum;
    __syncthreads();
#pragma unroll
    for (int o = 1; o < 1024; o <<= 1) {
        int tmp = (t >= o) ? s[t - o] : 0;
        __syncthreads();
        s[t] += tmp;
        __syncthreads();
    }
    int run = s[t] - sum;
    for (int i = beg; i < end_; ++i) { int v = data[i]; data[i] = run; run += v; }
}

// ---------------------------------------------------------------------------
// K5: scatter items into bin-contiguous order via LDS cursors.
// ---------------------------------------------------------------------------
__global__ void k_bin_scatter(const ull* __restrict__ items,
                              const int* __restrict__ bhist,
                              const int* __restrict__ bsum,
                              ull* __restrict__ binned,
                              int E2, int nblkH, int NBG) {
    __shared__ int cursor[1024];
    for (int i = threadIdx.x; i < NBG; i += BLK) {
        int idx = i * nblkH + blockIdx.x;
        cursor[i] = bhist[idx] + bsum[idx >> 8];
    }
    __syncthreads();
    int base = blockIdx.x * PAIRS_PER_CHUNK;
#pragma unroll
    for (int k = 0; k < IPT; ++k) {
        int i = base + k * BLK + threadIdx.x;
        if (i < E2) {
            ull it = items[i];
            int pos = atomicAdd(&cursor[(int)(it >> (48 + GBITS))], 1);
            binned[pos] = it;
            ull it2 = items[i + E2];
            int pos2 = atomicAdd(&cursor[(int)(it2 >> (48 + GBITS))], 1);
            binned[pos2] = it2;
        }
    }
}

// ---------------------------------------------------------------------------
// K6: per-group diag: rdiag[r] = sum m^2 (LDS atomics) -> dsi, diag2.
// ---------------------------------------------------------------------------
__global__ void k_diag(const ull* __restrict__ binned,
                       const int* __restrict__ bhist,
                       const int* __restrict__ bsum,
                       float* __restrict__ dsi, float* __restrict__ diag2,
                       int E, int nblkH, int NBG, int N) {
    __shared__ float rdiag[GSIZE];
    __shared__ int sgs[2];
    int g = blockIdx.x, t = threadIdx.x;
    if (t < GSIZE) rdiag[t] = 0.f;
    if (t < 2) {
        int gg = g + t;
        if (gg < NBG) {
            int idx = gg * nblkH;
            sgs[t] = bhist[idx] + bsum[idx >> 8];
        } else sgs[t] = E;
    }
    __syncthreads();
    int gstart = sgs[0], gend = sgs[1];
    for (int k = gstart + t; k < gend; k += BLK) {
        ull it = binned[k];
        int r = (int)(it >> 48) & (GSIZE - 1);
        float m = h2f((unsigned short)((it >> 16) & 0xFFFF));
        atomicAdd(&rdiag[r], m * m);
    }
    __syncthreads();
    int n = (g << GBITS) + t;
    if (t < GSIZE && n < N) {
        float dm = rdiag[t];
        float ds = rsqrtf(dm + 1.0f);
        dsi[n] = ds;
        diag2[n] = dm * ds * ds;
    }
}

// ---------------------------------------------------------------------------
// K7: per-group accumulate + finalize.  One item per half-wave; lane d owns
//     dim d; LDS atomicAdd into acc[64][32] is bank-conflict-free.
//     out = x - diag2[n]*y + dsi[n] * acc,  acc = sum m*mr*dsi[col]*y[col,:]
// ---------------------------------------------------------------------------
__global__ __launch_bounds__(512) void k_accum(
        const ull* __restrict__ binned,
        const int* __restrict__ bhist,
        const int* __restrict__ bsum,
        const float* __restrict__ y,
        const float* __restrict__ x,
        const float* __restrict__ dsi,
        const float* __restrict__ diag2,
        float* __restrict__ out,
        int E, int nblkH, int NBG, int N) {
    __shared__ float acc[GSIZE * D];   // 8 KB
    __shared__ int sgs[2];
    int g = blockIdx.x, t = threadIdx.x;
    for (int i = t; i < GSIZE * D; i += 512) acc[i] = 0.f;
    if (t < 2) {
        int gg = g + t;
        if (gg < NBG) {
            int idx = gg * nblkH;
            sgs[t] = bhist[idx] + bsum[idx >> 8];
        } else sgs[t] = E;
    }
    __syncthreads();
    int gstart = sgs[0], gend = sgs[1];
    int hw = t >> 5;            // 16 half-waves
    int lane = t & 31;
    for (int k = gstart + hw; k < gend; k += 16) {
        ull it = binned[k];
        int r = (int)(it >> 48) & (GSIZE - 1);
        int c = (int)((it >> 32) & 0xFFFF);
        float w = h2f((unsigned short)((it >> 16) & 0xFFFF)) *
                  h2f((unsigned short)(it & 0xFFFF)) * dsi[c];
        atomicAdd(&acc[r * D + lane], w * y[(size_t)c * D + lane]);
    }
    __syncthreads();
    int rows = min(GSIZE, N - (g << GBITS));
    for (int i = t; i < rows * D; i += 512) {
        int r = i >> 5;
        int n = (g << GBITS) + r;
        size_t p = (size_t)n * D + (i & 31);
        out[p] = x[p] - diag2[n] * y[p] + dsi[n] * acc[i];
    }
}

extern "C" void kernel_launch(void* const* d_in, const int* in_sizes, int n_in,
                              void* d_out, int out_size, void* d_ws, size_t ws_size,
                              hipStream_t stream) {
    const float* x      = (const float*)d_in[0];
    const float* sheafW = (const float*)d_in[1];
    const float* linW   = (const float*)d_in[2];
    const float* linb   = (const float*)d_in[3];
    const int*   ei     = (const int*)d_in[4];

    int N  = in_sizes[0] / D;
    int E  = in_sizes[4] / 2;
    int E2 = E / 2;

    int NBG   = (N + GSIZE - 1) >> GBITS;                        // 782
    int nblkH = (E2 + PAIRS_PER_CHUNK - 1) / PAIRS_PER_CHUNK;    // 782
    int MH    = NBG * nblkH;                                     // ~611K
    int nblkA = (MH + 255) / 256;                                // ~2389

    // Workspace (8B aligned first):
    // items[E] u64 | binned[E] u64 | ab[N] float2 | y[N*D] f32 |
    // dsi[N] | diag2[N] | bhist[MH] | bsumA[nblkA]
    char* wp = (char*)d_ws;
    ull*    items  = (ull*)wp;    wp += (size_t)E * 8;
    ull*    binned = (ull*)wp;    wp += (size_t)E * 8;
    float2* ab     = (float2*)wp; wp += (size_t)N * 8;
    float*  y      = (float*)wp;  wp += (size_t)N * D * 4;
    float*  dsi    = (float*)wp;  wp += (size_t)N * 4;
    float*  diag2  = (float*)wp;  wp += (size_t)N * 4;
    int*    bhist  = (int*)wp;    wp += (size_t)MH * 4;
    int*    bsumA  = (int*)wp;    wp += (size_t)nblkA * 4;

    float* out = (float*)d_out;

    int nbN = (N + BLK - 1) / BLK;

    k_node_pre<<<nbN, BLK, 0, stream>>>(x, sheafW, linW, linb, ab, y, N);
    k_edge_items_hist<<<nblkH, BLK, 0, stream>>>(ei, ab, items, bhist, E2, E, nblkH, NBG);
    k_scanA<<<nblkA, 256, 0, stream>>>(bhist, bsumA, MH);
    k_scanB<<<1, 1024, 0, stream>>>(bsumA, nblkA);
    k_bin_scatter<<<nblkH, BLK, 0, stream>>>(items, bhist, bsumA, binned, E2, nblkH, NBG);
    k_diag<<<NBG, BLK, 0, stream>>>(binned, bhist, bsumA, dsi, diag2, E, nblkH, NBG, N);
    k_accum<<<NBG, 512, 0, stream>>>(binned, bhist, bsumA, y, x, dsi, diag2, out,
                                     E, nblkH, NBG, N);
}

// Round 7
// 112.199 us; speedup vs baseline: 3.8064x; 3.8064x over previous
//
#include <hip/hip_runtime.h>

#define D 32
#define GBITS 6
#define GSIZE 64               // rows per group
#define BLK 256
#define PPC 2048               // pairs per hist/scatter chunk
#define IPT 8                  // PPC / BLK
#define CAP 2560               // LDS item capacity per group (mean 2048, std 45)

typedef unsigned long long ull;

static __device__ __forceinline__ unsigned short f2h(float f) {
    _Float16 h = (_Float16)f;
    return __builtin_bit_cast(unsigned short, h);
}
static __device__ __forceinline__ float h2f(unsigned short u) {
    return (float)__builtin_bit_cast(_Float16, u);
}

// ---------------------------------------------------------------------------
// K1: per-node precompute.  ab[n] = (x[n].sheafW[0:D], x[n].sheafW[D:2D])
//     y[n,:] = lin_W @ x[n] + lin_b
// ---------------------------------------------------------------------------
__global__ void k_node_pre(const float* __restrict__ x,
                           const float* __restrict__ sheafW,
                           const float* __restrict__ linW,
                           const float* __restrict__ linb,
                           float2* __restrict__ ab,
                           float* __restrict__ y, int N) {
    __shared__ float sW[D * D];
    __shared__ float sB[D];
    __shared__ float sS[2 * D];
    for (int i = threadIdx.x; i < D * D; i += blockDim.x) sW[i] = linW[i];
    if (threadIdx.x < D) sB[threadIdx.x] = linb[threadIdx.x];
    if (threadIdx.x < 2 * D) sS[threadIdx.x] = sheafW[threadIdx.x];
    __syncthreads();

    int n = blockIdx.x * blockDim.x + threadIdx.x;
    if (n >= N) return;

    float xv[D];
    const float4* xp = reinterpret_cast<const float4*>(x + (size_t)n * D);
#pragma unroll
    for (int i = 0; i < D / 4; ++i) {
        float4 v = xp[i];
        xv[4 * i + 0] = v.x; xv[4 * i + 1] = v.y;
        xv[4 * i + 2] = v.z; xv[4 * i + 3] = v.w;
    }

    float av = 0.f, bv = 0.f;
#pragma unroll
    for (int d = 0; d < D; ++d) { av += xv[d] * sS[d]; bv += xv[d] * sS[D + d]; }
    ab[n] = make_float2(av, bv);

    float4* yp = reinterpret_cast<float4*>(y + (size_t)n * D);
#pragma unroll
    for (int j4 = 0; j4 < D / 4; ++j4) {
        float4 o;
#pragma unroll
        for (int jj = 0; jj < 4; ++jj) {
            int j = 4 * j4 + jj;
            float s = sB[j];
#pragma unroll
            for (int d = 0; d < D; ++d) s += xv[d] * sW[j * D + d];
            (&o.x)[jj] = s;
        }
        yp[j4] = o;
    }
}

// ---------------------------------------------------------------------------
// K2: per undirected pair -> two packed items (row<<48|col<<32|m16|mr16)
//     fused with blocked histogram of bin = row >> GBITS.
//     (N <= 65535 so row/col fit 16 bits.)
// ---------------------------------------------------------------------------
__global__ void k_edge_items_hist(const int* __restrict__ ei,
                                  const float2* __restrict__ ab,
                                  ull* __restrict__ items,
                                  int* __restrict__ bhist,
                                  int E2, int E, int nblkH, int NBG) {
    __shared__ int hist[1024];
    for (int i = threadIdx.x; i < NBG; i += BLK) hist[i] = 0;
    __syncthreads();
    int base = blockIdx.x * PPC;
#pragma unroll
    for (int k = 0; k < IPT; ++k) {
        int i = base + k * BLK + threadIdx.x;
        if (i < E2) {
            int s = ei[i];
            int t = ei[E + i];
            float2 as = ab[s], at = ab[t];
            float m  = tanhf(as.x + at.y);
            float mr = tanhf(at.x + as.y);
            ull hm = f2h(m), hmr = f2h(mr);
            items[i]      = ((ull)(unsigned)s << 48) | ((ull)(unsigned)t << 32) | (hm << 16) | hmr;
            items[i + E2] = ((ull)(unsigned)t << 48) | ((ull)(unsigned)s << 32) | (hmr << 16) | hm;
            atomicAdd(&hist[s >> GBITS], 1);
            atomicAdd(&hist[t >> GBITS], 1);
        }
    }
    __syncthreads();
    for (int i = threadIdx.x; i < NBG; i += BLK)
        bhist[(size_t)i * nblkH + blockIdx.x] = hist[i];
}

// ---------------------------------------------------------------------------
// Scan level A: 256-elem blocks, local exclusive in place + block sums.
// ---------------------------------------------------------------------------
__global__ void k_scanA(int* __restrict__ data, int* __restrict__ bsum, int M) {
    __shared__ int s[256];
    int t = threadIdx.x;
    int i = blockIdx.x * 256 + t;
    int v = (i < M) ? data[i] : 0;
    s[t] = v;
    __syncthreads();
#pragma unroll
    for (int o = 1; o < 256; o <<= 1) {
        int tmp = (t >= o) ? s[t - o] : 0;
        __syncthreads();
        s[t] += tmp;
        __syncthreads();
    }
    if (i < M) data[i] = s[t] - v;
    if (t == 255) bsum[blockIdx.x] = s[255];
}

// ---------------------------------------------------------------------------
// Scan level B: one 1024-thread block, in-place exclusive scan of NB elems
// (each thread owns a contiguous chunk).
// ---------------------------------------------------------------------------
__global__ void k_scanB(int* __restrict__ data, int NB) {
    __shared__ int s[1024];
    int t = threadIdx.x;
    int per = (NB + 1023) >> 10;
    int beg = t * per;
    int end_ = min(beg + per, NB);
    int sum = 0;
    for (int i = beg; i < end_; ++i) sum += data[i];
    s[t] = sum;
    __syncthreads();
#pragma unroll
    for (int o = 1; o < 1024; o <<= 1) {
        int tmp = (t >= o) ? s[t - o] : 0;
        __syncthreads();
        s[t] += tmp;
        __syncthreads();
    }
    int run = s[t] - sum;
    for (int i = beg; i < end_; ++i) { int v = data[i]; data[i] = run; run += v; }
}

// ---------------------------------------------------------------------------
// K5: scatter items into group-contiguous order via LDS cursors.
// ---------------------------------------------------------------------------
__global__ void k_bin_scatter(const ull* __restrict__ items,
                              const int* __restrict__ bhist,
                              const int* __restrict__ bsum,
                              ull* __restrict__ binned,
                              int E2, int nblkH, int NBG) {
    __shared__ int cursor[1024];
    for (int i = threadIdx.x; i < NBG; i += BLK) {
        int idx = i * nblkH + blockIdx.x;
        cursor[i] = bhist[idx] + bsum[idx >> 8];
    }
    __syncthreads();
    int base = blockIdx.x * PPC;
#pragma unroll
    for (int k = 0; k < IPT; ++k) {
        int i = base + k * BLK + threadIdx.x;
        if (i < E2) {
            ull it = items[i];
            int pos = atomicAdd(&cursor[(int)(it >> (48 + GBITS))], 1);
            binned[pos] = it;
            ull it2 = items[i + E2];
            int pos2 = atomicAdd(&cursor[(int)(it2 >> (48 + GBITS))], 1);
            binned[pos2] = it2;
        }
    }
}

// ---------------------------------------------------------------------------
// K6: per-group diag (scalar LDS f32 atomics, 1/item) -> dsi, diag2,
//     and z_h = f16(dsi * y) for the group's rows.
// ---------------------------------------------------------------------------
__global__ void k_diag_zscale(const ull* __restrict__ binned,
                              const int* __restrict__ bhist,
                              const int* __restrict__ bsum,
                              const float* __restrict__ y,
                              float* __restrict__ dsi, float* __restrict__ diag2,
                              unsigned short* __restrict__ z_h,
                              int E, int nblkH, int NBG, int N) {
    __shared__ float rdiag[GSIZE];
    __shared__ float sds[GSIZE];
    __shared__ int sgs[2];
    int g = blockIdx.x, t = threadIdx.x;
    if (t < GSIZE) rdiag[t] = 0.f;
    if (t < 2) {
        int gg = g + t;
        if (gg < NBG) {
            int idx = gg * nblkH;
            sgs[t] = bhist[idx] + bsum[idx >> 8];
        } else sgs[t] = E;
    }
    __syncthreads();
    int gstart = sgs[0], gend = sgs[1];
    for (int k = gstart + t; k < gend; k += BLK) {
        ull it = binned[k];
        int r = (int)(it >> 48) & (GSIZE - 1);
        float m = h2f((unsigned short)((it >> 16) & 0xFFFF));
        atomicAdd(&rdiag[r], m * m);
    }
    __syncthreads();
    int n0 = g << GBITS;
    if (t < GSIZE) {
        int n = n0 + t;
        if (n < N) {
            float dm = rdiag[t];
            float ds = rsqrtf(dm + 1.0f);
            dsi[n] = ds;
            diag2[n] = dm * ds;          // diag/dsi = dm*ds  (diag2*z == diag*y)
            sds[t] = ds;
        }
    }
    __syncthreads();
    int rows = min(GSIZE, N - n0);
    for (int i = t; i < rows * D; i += BLK) {
        int r = i >> 5;
        size_t p = (size_t)(n0 + r) * D + (i & 31);
        z_h[p] = f2h(sds[r] * y[p]);
    }
}

// ---------------------------------------------------------------------------
// K7: fused sort+gather per group.  Items staged in LDS, row-sorted in LDS
//     (scalar int atomics only), then 16 half-waves walk row segments.
//     out = x - diag2[n]*z[n,:] + dsi[n] * sum m*mr * z[col,:]
// ---------------------------------------------------------------------------
__global__ __launch_bounds__(512) void k_gather_fused(
        const ull* __restrict__ binned,
        const int* __restrict__ bhist,
        const int* __restrict__ bsum,
        const unsigned short* __restrict__ z_h,
        const float* __restrict__ x,
        const float* __restrict__ dsi,
        const float* __restrict__ diag2,
        float* __restrict__ out,
        int E, int nblkH, int NBG, int N) {
    __shared__ ull raw[CAP];
    __shared__ ull sorted[CAP];
    __shared__ int rhist[GSIZE];
    __shared__ int rbase[GSIZE];
    __shared__ int cur[GSIZE];
    __shared__ float sds[GSIZE];
    __shared__ float sdg[GSIZE];
    __shared__ int ss[GSIZE];
    __shared__ int sgs[2];
    int g = blockIdx.x, t = threadIdx.x;
    int n0 = g << GBITS;
    if (t < GSIZE) {
        rhist[t] = 0;
        int n = n0 + t;
        if (n < N) { sds[t] = dsi[n]; sdg[t] = diag2[n]; }
    }
    if (t < 2) {
        int gg = g + t;
        if (gg < NBG) {
            int idx = gg * nblkH;
            sgs[t] = bhist[idx] + bsum[idx >> 8];
        } else sgs[t] = E;
    }
    __syncthreads();
    int gstart = sgs[0];
    int cnt = min(sgs[1] - gstart, CAP);

    // load items to LDS + row histogram (1 scalar atomic per item)
    for (int k = t; k < cnt; k += 512) {
        ull it = binned[gstart + k];
        raw[k] = it;
        atomicAdd(&rhist[(int)(it >> 48) & (GSIZE - 1)], 1);
    }
    __syncthreads();

    // exclusive scan of rhist (64 entries; barriers hit by all 512 threads)
    int v = (t < GSIZE) ? rhist[t] : 0;
    if (t < GSIZE) ss[t] = v;
    __syncthreads();
#pragma unroll
    for (int o = 1; o < GSIZE; o <<= 1) {
        int tmp = 0;
        if (t < GSIZE && t >= o) tmp = ss[t - o];
        __syncthreads();
        if (t < GSIZE) ss[t] += tmp;
        __syncthreads();
    }
    if (t < GSIZE) {
        int ex = ss[t] - v;
        rbase[t] = ex;
        cur[t] = ex;
    }
    __syncthreads();

    // counting-scatter to row-sorted LDS order (1 scalar atomic per item)
    for (int k = t; k < cnt; k += 512) {
        ull it = raw[k];
        int r = (int)(it >> 48) & (GSIZE - 1);
        int pos = atomicAdd(&cur[r], 1);
        sorted[pos] = it;
    }
    __syncthreads();

    // walk: 16 half-waves, each owns rows hw, hw+16, ...; lane = dim
    int hw = t >> 5;
    int lane = t & 31;
    int rows = min(GSIZE, N - n0);
    for (int r = hw; r < rows; r += 16) {
        int beg = rbase[r];
        int end_ = beg + rhist[r];
        float acc = 0.f;
        int k = beg;
        for (; k + 4 <= end_; k += 4) {
            ull i0 = sorted[k + 0];
            ull i1 = sorted[k + 1];
            ull i2 = sorted[k + 2];
            ull i3 = sorted[k + 3];
            int c0 = (int)((i0 >> 32) & 0xFFFF);
            int c1 = (int)((i1 >> 32) & 0xFFFF);
            int c2 = (int)((i2 >> 32) & 0xFFFF);
            int c3 = (int)((i3 >> 32) & 0xFFFF);
            float v0 = h2f(z_h[(size_t)c0 * D + lane]);
            float v1 = h2f(z_h[(size_t)c1 * D + lane]);
            float v2 = h2f(z_h[(size_t)c2 * D + lane]);
            float v3 = h2f(z_h[(size_t)c3 * D + lane]);
            acc += h2f((unsigned short)((i0 >> 16) & 0xFFFF)) * h2f((unsigned short)(i0 & 0xFFFF)) * v0;
            acc += h2f((unsigned short)((i1 >> 16) & 0xFFFF)) * h2f((unsigned short)(i1 & 0xFFFF)) * v1;
            acc += h2f((unsigned short)((i2 >> 16) & 0xFFFF)) * h2f((unsigned short)(i2 & 0xFFFF)) * v2;
            acc += h2f((unsigned short)((i3 >> 16) & 0xFFFF)) * h2f((unsigned short)(i3 & 0xFFFF)) * v3;
        }
        for (; k < end_; ++k) {
            ull it = sorted[k];
            int c = (int)((it >> 32) & 0xFFFF);
            acc += h2f((unsigned short)((it >> 16) & 0xFFFF)) * h2f((unsigned short)(it & 0xFFFF)) *
                   h2f(z_h[(size_t)c * D + lane]);
        }
        size_t p = (size_t)(n0 + r) * D + lane;
        float zown = h2f(z_h[p]);
        out[p] = x[p] - sdg[r] * zown + sds[r] * acc;
    }
}

extern "C" void kernel_launch(void* const* d_in, const int* in_sizes, int n_in,
                              void* d_out, int out_size, void* d_ws, size_t ws_size,
                              hipStream_t stream) {
    const float* x      = (const float*)d_in[0];
    const float* sheafW = (const float*)d_in[1];
    const float* linW   = (const float*)d_in[2];
    const float* linb   = (const float*)d_in[3];
    const int*   ei     = (const int*)d_in[4];

    int N  = in_sizes[0] / D;
    int E  = in_sizes[4] / 2;
    int E2 = E / 2;

    int NBG   = (N + GSIZE - 1) >> GBITS;          // 782
    int nblkH = (E2 + PPC - 1) / PPC;              // 391
    int MH    = NBG * nblkH;                       // ~306K
    int nblkA = (MH + 255) / 256;                  // ~1195

    // Workspace (8B aligned first):
    // items[E] u64 | binned[E] u64 | ab[N] float2 | y[N*D] f32 |
    // dsi[N] | diag2[N] | z_h[N*D] u16 | bhist[MH] | bsumA[nblkA]
    char* wp = (char*)d_ws;
    ull*    items  = (ull*)wp;    wp += (size_t)E * 8;
    ull*    binned = (ull*)wp;    wp += (size_t)E * 8;
    float2* ab     = (float2*)wp; wp += (size_t)N * 8;
    float*  y      = (float*)wp;  wp += (size_t)N * D * 4;
    float*  dsi    = (float*)wp;  wp += (size_t)N * 4;
    float*  diag2  = (float*)wp;  wp += (size_t)N * 4;
    unsigned short* z_h = (unsigned short*)wp; wp += (size_t)N * D * 2;
    int*    bhist  = (int*)wp;    wp += (size_t)MH * 4;
    int*    bsumA  = (int*)wp;    wp += (size_t)nblkA * 4;

    float* out = (float*)d_out;

    int nbN = (N + BLK - 1) / BLK;

    k_node_pre<<<nbN, BLK, 0, stream>>>(x, sheafW, linW, linb, ab, y, N);
    k_edge_items_hist<<<nblkH, BLK, 0, stream>>>(ei, ab, items, bhist, E2, E, nblkH, NBG);
    k_scanA<<<nblkA, 256, 0, stream>>>(bhist, bsumA, MH);
    k_scanB<<<1, 1024, 0, stream>>>(bsumA, nblkA);
    k_bin_scatter<<<nblkH, BLK, 0, stream>>>(items, bhist, bsumA, binned, E2, nblkH, NBG);
    k_diag_zscale<<<NBG, BLK, 0, stream>>>(binned, bhist, bsumA, y, dsi, diag2, z_h,
                                           E, nblkH, NBG, N);
    k_gather_fused<<<NBG, 512, 0, stream>>>(binned, bhist, bsumA, z_h, x, dsi, diag2,
                                            out, E, nblkH, NBG, N);
}

// Round 8
// 105.001 us; speedup vs baseline: 4.0674x; 1.0686x over previous
//
#include <hip/hip_runtime.h>

#define D 32
#define GBITS 6
#define GSIZE 64               // rows per group
#define BLK 256
#define PPC 2048               // pairs per hist/scatter chunk
#define IPT 8                  // PPC / BLK
#define CAP 2560               // LDS item capacity per group (mean 2048, std ~45)

typedef unsigned long long ull;

static __device__ __forceinline__ unsigned short f2h(float f) {
    _Float16 h = (_Float16)f;
    return __builtin_bit_cast(unsigned short, h);
}
static __device__ __forceinline__ float h2f(unsigned short u) {
    return (float)__builtin_bit_cast(_Float16, u);
}
static __device__ __forceinline__ float ftanh(float u) {
    u = fminf(fmaxf(u, -15.f), 15.f);
    float e = __expf(2.f * u);
    return (e - 1.f) / (e + 1.f);
}

// ---------------------------------------------------------------------------
// K1 (fused): blocks [0,nbN) do per-node precompute; blocks [nbN,...) do the
// blocked bin histogram (bin = row >> GBITS) over edge pairs.  No dependency
// between the two paths; whole blocks take one branch.
// ---------------------------------------------------------------------------
__global__ void k_pre_hist(const float* __restrict__ x,
                           const float* __restrict__ sheafW,
                           const float* __restrict__ linW,
                           const float* __restrict__ linb,
                           const int* __restrict__ ei,
                           float2* __restrict__ ab,
                           float* __restrict__ y,
                           int* __restrict__ bhist,
                           int N, int E2, int E, int nbN, int nblkH, int NBG) {
    if (blockIdx.x < nbN) {
        __shared__ float sW[D * D];
        __shared__ float sB[D];
        __shared__ float sS[2 * D];
        for (int i = threadIdx.x; i < D * D; i += blockDim.x) sW[i] = linW[i];
        if (threadIdx.x < D) sB[threadIdx.x] = linb[threadIdx.x];
        if (threadIdx.x < 2 * D) sS[threadIdx.x] = sheafW[threadIdx.x];
        __syncthreads();

        int n = blockIdx.x * blockDim.x + threadIdx.x;
        if (n >= N) return;

        float xv[D];
        const float4* xp = reinterpret_cast<const float4*>(x + (size_t)n * D);
#pragma unroll
        for (int i = 0; i < D / 4; ++i) {
            float4 v = xp[i];
            xv[4 * i + 0] = v.x; xv[4 * i + 1] = v.y;
            xv[4 * i + 2] = v.z; xv[4 * i + 3] = v.w;
        }

        float av = 0.f, bv = 0.f;
#pragma unroll
        for (int d = 0; d < D; ++d) { av += xv[d] * sS[d]; bv += xv[d] * sS[D + d]; }
        ab[n] = make_float2(av, bv);

        float4* yp = reinterpret_cast<float4*>(y + (size_t)n * D);
#pragma unroll
        for (int j4 = 0; j4 < D / 4; ++j4) {
            float4 o;
#pragma unroll
            for (int jj = 0; jj < 4; ++jj) {
                int j = 4 * j4 + jj;
                float s = sB[j];
#pragma unroll
                for (int d = 0; d < D; ++d) s += xv[d] * sW[j * D + d];
                (&o.x)[jj] = s;
            }
            yp[j4] = o;
        }
    } else {
        __shared__ int hist[1024];
        int blk = blockIdx.x - nbN;
        for (int i = threadIdx.x; i < NBG; i += BLK) hist[i] = 0;
        __syncthreads();
        int base = blk * PPC;
#pragma unroll
        for (int k = 0; k < IPT; ++k) {
            int i = base + k * BLK + threadIdx.x;
            if (i < E2) {
                int s = ei[i];
                int t = ei[E + i];
                atomicAdd(&hist[s >> GBITS], 1);
                atomicAdd(&hist[t >> GBITS], 1);
            }
        }
        __syncthreads();
        for (int i = threadIdx.x; i < NBG; i += BLK)
            bhist[(size_t)i * nblkH + blk] = hist[i];
    }
}

// ---------------------------------------------------------------------------
// Scan level A: 256-elem blocks, local exclusive in place + block sums.
// ---------------------------------------------------------------------------
__global__ void k_scanA(int* __restrict__ data, int* __restrict__ bsum, int M) {
    __shared__ int s[256];
    int t = threadIdx.x;
    int i = blockIdx.x * 256 + t;
    int v = (i < M) ? data[i] : 0;
    s[t] = v;
    __syncthreads();
#pragma unroll
    for (int o = 1; o < 256; o <<= 1) {
        int tmp = (t >= o) ? s[t - o] : 0;
        __syncthreads();
        s[t] += tmp;
        __syncthreads();
    }
    if (i < M) data[i] = s[t] - v;
    if (t == 255) bsum[blockIdx.x] = s[255];
}

// ---------------------------------------------------------------------------
// Scan level B: one 1024-thread block, in-place exclusive scan of NB elems.
// ---------------------------------------------------------------------------
__global__ void k_scanB(int* __restrict__ data, int NB) {
    __shared__ int s[1024];
    int t = threadIdx.x;
    int per = (NB + 1023) >> 10;
    int beg = t * per;
    int end_ = min(beg + per, NB);
    int sum = 0;
    for (int i = beg; i < end_; ++i) sum += data[i];
    s[t] = sum;
    __syncthreads();
#pragma unroll
    for (int o = 1; o < 1024; o <<= 1) {
        int tmp = (t >= o) ? s[t - o] : 0;
        __syncthreads();
        s[t] += tmp;
        __syncthreads();
    }
    int run = s[t] - sum;
    for (int i = beg; i < end_; ++i) { int v = data[i]; data[i] = run; run += v; }
}

// ---------------------------------------------------------------------------
// K4: scatter — recomputes maps from ab (no items array), packs
//     (row<<48|col<<32|m16|mr16) and writes directly to binned order.
// ---------------------------------------------------------------------------
__global__ void k_scatter(const int* __restrict__ ei,
                          const float2* __restrict__ ab,
                          const int* __restrict__ bhist,
                          const int* __restrict__ bsum,
                          ull* __restrict__ binned,
                          int E2, int E, int nblkH, int NBG) {
    __shared__ int cursor[1024];
    for (int i = threadIdx.x; i < NBG; i += BLK) {
        int idx = i * nblkH + blockIdx.x;
        cursor[i] = bhist[idx] + bsum[idx >> 8];
    }
    __syncthreads();
    int base = blockIdx.x * PPC;
#pragma unroll
    for (int k = 0; k < IPT; ++k) {
        int i = base + k * BLK + threadIdx.x;
        if (i < E2) {
            int s = ei[i];
            int t = ei[E + i];
            float2 as = ab[s], at = ab[t];
            float m  = ftanh(as.x + at.y);
            float mr = ftanh(at.x + as.y);
            ull hm = f2h(m), hmr = f2h(mr);
            int pos = atomicAdd(&cursor[s >> GBITS], 1);
            binned[pos] = ((ull)(unsigned)s << 48) | ((ull)(unsigned)t << 32) | (hm << 16) | hmr;
            int pos2 = atomicAdd(&cursor[t >> GBITS], 1);
            binned[pos2] = ((ull)(unsigned)t << 48) | ((ull)(unsigned)s << 32) | (hmr << 16) | hm;
        }
    }
}

// ---------------------------------------------------------------------------
// K5: per-group diag (scalar LDS f32 atomics, 1/item) -> dsi, diag2,
//     and z_h = f16(dsi * y) for the group's rows.
// ---------------------------------------------------------------------------
__global__ void k_diag_zscale(const ull* __restrict__ binned,
                              const int* __restrict__ bhist,
                              const int* __restrict__ bsum,
                              const float* __restrict__ y,
                              float* __restrict__ dsi, float* __restrict__ diag2,
                              unsigned short* __restrict__ z_h,
                              int E, int nblkH, int NBG, int N) {
    __shared__ float rdiag[GSIZE];
    __shared__ float sds[GSIZE];
    __shared__ int sgs[2];
    int g = blockIdx.x, t = threadIdx.x;
    if (t < GSIZE) rdiag[t] = 0.f;
    if (t < 2) {
        int gg = g + t;
        if (gg < NBG) {
            int idx = gg * nblkH;
            sgs[t] = bhist[idx] + bsum[idx >> 8];
        } else sgs[t] = E;
    }
    __syncthreads();
    int gstart = sgs[0], gend = sgs[1];
    for (int k = gstart + t; k < gend; k += BLK) {
        ull it = binned[k];
        int r = (int)(it >> 48) & (GSIZE - 1);
        float m = h2f((unsigned short)((it >> 16) & 0xFFFF));
        atomicAdd(&rdiag[r], m * m);
    }
    __syncthreads();
    int n0 = g << GBITS;
    if (t < GSIZE) {
        int n = n0 + t;
        if (n < N) {
            float dm = rdiag[t];
            float ds = rsqrtf(dm + 1.0f);
            dsi[n] = ds;
            diag2[n] = dm * ds;          // diag/dsi = dm*ds  (diag2*z == diag*y)
            sds[t] = ds;
        }
    }
    __syncthreads();
    int rows = min(GSIZE, N - n0);
    for (int i = t; i < rows * D; i += BLK) {
        int r = i >> 5;
        size_t p = (size_t)(n0 + r) * D + (i & 31);
        z_h[p] = f2h(sds[r] * y[p]);
    }
}

// ---------------------------------------------------------------------------
// K6: fused sort+gather per group.  Items staged in LDS, row-sorted in LDS
//     (scalar int atomics only), then 16 half-waves walk row segments.
//     out = x - diag2[n]*z[n,:] + dsi[n] * sum m*mr * z[col,:]
// ---------------------------------------------------------------------------
__global__ __launch_bounds__(512) void k_gather_fused(
        const ull* __restrict__ binned,
        const int* __restrict__ bhist,
        const int* __restrict__ bsum,
        const unsigned short* __restrict__ z_h,
        const float* __restrict__ x,
        const float* __restrict__ dsi,
        const float* __restrict__ diag2,
        float* __restrict__ out,
        int E, int nblkH, int NBG, int N) {
    __shared__ ull raw[CAP];
    __shared__ ull sorted[CAP];
    __shared__ int rhist[GSIZE];
    __shared__ int rbase[GSIZE];
    __shared__ int cur[GSIZE];
    __shared__ float sds[GSIZE];
    __shared__ float sdg[GSIZE];
    __shared__ int ss[GSIZE];
    __shared__ int sgs[2];
    int g = blockIdx.x, t = threadIdx.x;
    int n0 = g << GBITS;
    if (t < GSIZE) {
        rhist[t] = 0;
        int n = n0 + t;
        if (n < N) { sds[t] = dsi[n]; sdg[t] = diag2[n]; }
    }
    if (t < 2) {
        int gg = g + t;
        if (gg < NBG) {
            int idx = gg * nblkH;
            sgs[t] = bhist[idx] + bsum[idx >> 8];
        } else sgs[t] = E;
    }
    __syncthreads();
    int gstart = sgs[0];
    int cnt = min(sgs[1] - gstart, CAP);

    // load items to LDS + row histogram (1 scalar atomic per item)
    for (int k = t; k < cnt; k += 512) {
        ull it = binned[gstart + k];
        raw[k] = it;
        atomicAdd(&rhist[(int)(it >> 48) & (GSIZE - 1)], 1);
    }
    __syncthreads();

    // exclusive scan of rhist (64 entries; barriers hit by all 512 threads)
    int v = (t < GSIZE) ? rhist[t] : 0;
    if (t < GSIZE) ss[t] = v;
    __syncthreads();
#pragma unroll
    for (int o = 1; o < GSIZE; o <<= 1) {
        int tmp = 0;
        if (t < GSIZE && t >= o) tmp = ss[t - o];
        __syncthreads();
        if (t < GSIZE) ss[t] += tmp;
        __syncthreads();
    }
    if (t < GSIZE) {
        int ex = ss[t] - v;
        rbase[t] = ex;
        cur[t] = ex;
    }
    __syncthreads();

    // counting-scatter to row-sorted LDS order (1 scalar atomic per item)
    for (int k = t; k < cnt; k += 512) {
        ull it = raw[k];
        int r = (int)(it >> 48) & (GSIZE - 1);
        int pos = atomicAdd(&cur[r], 1);
        sorted[pos] = it;
    }
    __syncthreads();

    // walk: 16 half-waves, each owns rows hw, hw+16, ...; lane = dim
    int hw = t >> 5;
    int lane = t & 31;
    int rows = min(GSIZE, N - n0);
    for (int r = hw; r < rows; r += 16) {
        int beg = rbase[r];
        int end_ = beg + rhist[r];
        float acc = 0.f;
        int k = beg;
        for (; k + 4 <= end_; k += 4) {
            ull i0 = sorted[k + 0];
            ull i1 = sorted[k + 1];
            ull i2 = sorted[k + 2];
            ull i3 = sorted[k + 3];
            int c0 = (int)((i0 >> 32) & 0xFFFF);
            int c1 = (int)((i1 >> 32) & 0xFFFF);
            int c2 = (int)((i2 >> 32) & 0xFFFF);
            int c3 = (int)((i3 >> 32) & 0xFFFF);
            float v0 = h2f(z_h[(size_t)c0 * D + lane]);
            float v1 = h2f(z_h[(size_t)c1 * D + lane]);
            float v2 = h2f(z_h[(size_t)c2 * D + lane]);
            float v3 = h2f(z_h[(size_t)c3 * D + lane]);
            acc += h2f((unsigned short)((i0 >> 16) & 0xFFFF)) * h2f((unsigned short)(i0 & 0xFFFF)) * v0;
            acc += h2f((unsigned short)((i1 >> 16) & 0xFFFF)) * h2f((unsigned short)(i1 & 0xFFFF)) * v1;
            acc += h2f((unsigned short)((i2 >> 16) & 0xFFFF)) * h2f((unsigned short)(i2 & 0xFFFF)) * v2;
            acc += h2f((unsigned short)((i3 >> 16) & 0xFFFF)) * h2f((unsigned short)(i3 & 0xFFFF)) * v3;
        }
        for (; k < end_; ++k) {
            ull it = sorted[k];
            int c = (int)((it >> 32) & 0xFFFF);
            acc += h2f((unsigned short)((it >> 16) & 0xFFFF)) * h2f((unsigned short)(it & 0xFFFF)) *
                   h2f(z_h[(size_t)c * D + lane]);
        }
        size_t p = (size_t)(n0 + r) * D + lane;
        float zown = h2f(z_h[p]);
        out[p] = x[p] - sdg[r] * zown + sds[r] * acc;
    }
}

extern "C" void kernel_launch(void* const* d_in, const int* in_sizes, int n_in,
                              void* d_out, int out_size, void* d_ws, size_t ws_size,
                              hipStream_t stream) {
    const float* x      = (const float*)d_in[0];
    const float* sheafW = (const float*)d_in[1];
    const float* linW   = (const float*)d_in[2];
    const float* linb   = (const float*)d_in[3];
    const int*   ei     = (const int*)d_in[4];

    int N  = in_sizes[0] / D;
    int E  = in_sizes[4] / 2;
    int E2 = E / 2;

    int NBG   = (N + GSIZE - 1) >> GBITS;          // 782
    int nblkH = (E2 + PPC - 1) / PPC;              // 391
    int MH    = NBG * nblkH;                       // ~306K
    int nblkA = (MH + 255) / 256;                  // ~1195

    // Workspace (8B aligned first):
    // binned[E] u64 | ab[N] float2 | y[N*D] f32 | dsi[N] | diag2[N] |
    // z_h[N*D] u16 | bhist[MH] | bsumA[nblkA]
    char* wp = (char*)d_ws;
    ull*    binned = (ull*)wp;    wp += (size_t)E * 8;
    float2* ab     = (float2*)wp; wp += (size_t)N * 8;
    float*  y      = (float*)wp;  wp += (size_t)N * D * 4;
    float*  dsi    = (float*)wp;  wp += (size_t)N * 4;
    float*  diag2  = (float*)wp;  wp += (size_t)N * 4;
    unsigned short* z_h = (unsigned short*)wp; wp += (size_t)N * D * 2;
    int*    bhist  = (int*)wp;    wp += (size_t)MH * 4;
    int*    bsumA  = (int*)wp;    wp += (size_t)nblkA * 4;

    float* out = (float*)d_out;

    int nbN = (N + BLK - 1) / BLK;                 // 196

    k_pre_hist<<<nbN + nblkH, BLK, 0, stream>>>(x, sheafW, linW, linb, ei, ab, y,
                                                bhist, N, E2, E, nbN, nblkH, NBG);
    k_scanA<<<nblkA, 256, 0, stream>>>(bhist, bsumA, MH);
    k_scanB<<<1, 1024, 0, stream>>>(bsumA, nblkA);
    k_scatter<<<nblkH, BLK, 0, stream>>>(ei, ab, bhist, bsumA, binned, E2, E, nblkH, NBG);
    k_diag_zscale<<<NBG, BLK, 0, stream>>>(binned, bhist, bsumA, y, dsi, diag2, z_h,
                                           E, nblkH, NBG, N);
    k_gather_fused<<<NBG, 512, 0, stream>>>(binned, bhist, bsumA, z_h, x, dsi, diag2,
                                            out, E, nblkH, NBG, N);
}

// Round 9
// 102.051 us; speedup vs baseline: 4.1849x; 1.0289x over previous
//
#include <hip/hip_runtime.h>

#define D 32
#define GBITS 6
#define GSIZE 64               // rows per group
#define BLK 256
#define PPC 4096               // pairs per hist/scatter chunk
#define IPT 16                 // PPC / BLK
#define CAP 2560               // LDS item capacity per group (mean 2048, ~11 sigma)

typedef unsigned long long ull;

static __device__ __forceinline__ unsigned short f2h(float f) {
    _Float16 h = (_Float16)f;
    return __builtin_bit_cast(unsigned short, h);
}
static __device__ __forceinline__ float h2f(unsigned short u) {
    return (float)__builtin_bit_cast(_Float16, u);
}
static __device__ __forceinline__ float ftanh(float u) {
    u = fminf(fmaxf(u, -15.f), 15.f);
    float e = __expf(2.f * u);
    return (e - 1.f) / (e + 1.f);
}

// ---------------------------------------------------------------------------
// K1 (fused): blocks [0,nbN) per-node precompute (ab + f16 y_h);
//             blocks [nbN,...) blocked bin histogram (bin = row >> GBITS).
// ---------------------------------------------------------------------------
__global__ void k_pre_hist(const float* __restrict__ x,
                           const float* __restrict__ sheafW,
                           const float* __restrict__ linW,
                           const float* __restrict__ linb,
                           const int* __restrict__ ei,
                           float2* __restrict__ ab,
                           unsigned short* __restrict__ y_h,
                           int* __restrict__ bhist,
                           int N, int E2, int E, int nbN, int nblkH, int NBG) {
    if (blockIdx.x < nbN) {
        __shared__ float sW[D * D];
        __shared__ float sB[D];
        __shared__ float sS[2 * D];
        for (int i = threadIdx.x; i < D * D; i += blockDim.x) sW[i] = linW[i];
        if (threadIdx.x < D) sB[threadIdx.x] = linb[threadIdx.x];
        if (threadIdx.x < 2 * D) sS[threadIdx.x] = sheafW[threadIdx.x];
        __syncthreads();

        int n = blockIdx.x * blockDim.x + threadIdx.x;
        if (n >= N) return;

        float xv[D];
        const float4* xp = reinterpret_cast<const float4*>(x + (size_t)n * D);
#pragma unroll
        for (int i = 0; i < D / 4; ++i) {
            float4 v = xp[i];
            xv[4 * i + 0] = v.x; xv[4 * i + 1] = v.y;
            xv[4 * i + 2] = v.z; xv[4 * i + 3] = v.w;
        }

        float av = 0.f, bv = 0.f;
#pragma unroll
        for (int d = 0; d < D; ++d) { av += xv[d] * sS[d]; bv += xv[d] * sS[D + d]; }
        ab[n] = make_float2(av, bv);

        unsigned short yh[D];
#pragma unroll
        for (int j = 0; j < D; ++j) {
            float s = sB[j];
#pragma unroll
            for (int d = 0; d < D; ++d) s += xv[d] * sW[j * D + d];
            yh[j] = f2h(s);
        }
        uint4* dst = reinterpret_cast<uint4*>(y_h + (size_t)n * D);
        const uint4* src = reinterpret_cast<const uint4*>(yh);
#pragma unroll
        for (int q = 0; q < D / 8; ++q) dst[q] = src[q];
    } else {
        __shared__ int hist[1024];
        int blk = blockIdx.x - nbN;
        for (int i = threadIdx.x; i < NBG; i += BLK) hist[i] = 0;
        __syncthreads();
        int base = blk * PPC;
#pragma unroll
        for (int k = 0; k < IPT; ++k) {
            int i = base + k * BLK + threadIdx.x;
            if (i < E2) {
                int s = ei[i];
                int t = ei[E + i];
                atomicAdd(&hist[s >> GBITS], 1);
                atomicAdd(&hist[t >> GBITS], 1);
            }
        }
        __syncthreads();
        for (int i = threadIdx.x; i < NBG; i += BLK)
            bhist[(size_t)i * nblkH + blk] = hist[i];
    }
}

// ---------------------------------------------------------------------------
// Scan level A: 256-elem blocks, local exclusive in place + block sums.
// ---------------------------------------------------------------------------
__global__ void k_scanA(int* __restrict__ data, int* __restrict__ bsum, int M) {
    __shared__ int s[256];
    int t = threadIdx.x;
    int i = blockIdx.x * 256 + t;
    int v = (i < M) ? data[i] : 0;
    s[t] = v;
    __syncthreads();
#pragma unroll
    for (int o = 1; o < 256; o <<= 1) {
        int tmp = (t >= o) ? s[t - o] : 0;
        __syncthreads();
        s[t] += tmp;
        __syncthreads();
    }
    if (i < M) data[i] = s[t] - v;
    if (t == 255) bsum[blockIdx.x] = s[255];
}

// ---------------------------------------------------------------------------
// Scan level B: one 1024-thread block, in-place exclusive scan of NB elems.
// ---------------------------------------------------------------------------
__global__ void k_scanB(int* __restrict__ data, int NB) {
    __shared__ int s[1024];
    int t = threadIdx.x;
    int per = (NB + 1023) >> 10;
    int beg = t * per;
    int end_ = min(beg + per, NB);
    int sum = 0;
    for (int i = beg; i < end_; ++i) sum += data[i];
    s[t] = sum;
    __syncthreads();
#pragma unroll
    for (int o = 1; o < 1024; o <<= 1) {
        int tmp = (t >= o) ? s[t - o] : 0;
        __syncthreads();
        s[t] += tmp;
        __syncthreads();
    }
    int run = s[t] - sum;
    for (int i = beg; i < end_; ++i) { int v = data[i]; data[i] = run; run += v; }
}

// ---------------------------------------------------------------------------
// K4: scatter — recomputes maps from ab, packs (row<<48|col<<32|m16|mr16),
//     writes directly into bin-grouped order via LDS cursors.
// ---------------------------------------------------------------------------
__global__ void k_scatter(const int* __restrict__ ei,
                          const float2* __restrict__ ab,
                          const int* __restrict__ bhist,
                          const int* __restrict__ bsum,
                          ull* __restrict__ binned,
                          int E2, int E, int nblkH, int NBG) {
    __shared__ int cursor[1024];
    for (int i = threadIdx.x; i < NBG; i += BLK) {
        int idx = i * nblkH + blockIdx.x;
        cursor[i] = bhist[idx] + bsum[idx >> 8];
    }
    __syncthreads();
    int base = blockIdx.x * PPC;
#pragma unroll
    for (int k = 0; k < IPT; ++k) {
        int i = base + k * BLK + threadIdx.x;
        if (i < E2) {
            int s = ei[i];
            int t = ei[E + i];
            float2 as = ab[s], at = ab[t];
            float m  = ftanh(as.x + at.y);
            float mr = ftanh(at.x + as.y);
            ull hm = f2h(m), hmr = f2h(mr);
            int pos = atomicAdd(&cursor[s >> GBITS], 1);
            binned[pos] = ((ull)(unsigned)s << 48) | ((ull)(unsigned)t << 32) | (hm << 16) | hmr;
            int pos2 = atomicAdd(&cursor[t >> GBITS], 1);
            binned[pos2] = ((ull)(unsigned)t << 48) | ((ull)(unsigned)s << 32) | (hmr << 16) | hm;
        }
    }
}

// ---------------------------------------------------------------------------
// K5: per-group diag (scalar LDS f32 atomics, 1/item) -> dsi, diag2 (=dm*ds^2).
// ---------------------------------------------------------------------------
__global__ void k_diag(const ull* __restrict__ binned,
                       const int* __restrict__ bhist,
                       const int* __restrict__ bsum,
                       float* __restrict__ dsi, float* __restrict__ diag2,
                       int E, int nblkH, int NBG, int N) {
    __shared__ float rdiag[GSIZE];
    __shared__ int sgs[2];
    int g = blockIdx.x, t = threadIdx.x;
    if (t < GSIZE) rdiag[t] = 0.f;
    if (t < 2) {
        int gg = g + t;
        if (gg < NBG) {
            int idx = gg * nblkH;
            sgs[t] = bhist[idx] + bsum[idx >> 8];
        } else sgs[t] = E;
    }
    __syncthreads();
    int gstart = sgs[0], gend = sgs[1];
    for (int k = gstart + t; k < gend; k += BLK) {
        ull it = binned[k];
        int r = (int)(it >> 48) & (GSIZE - 1);
        float m = h2f((unsigned short)((it >> 16) & 0xFFFF));
        atomicAdd(&rdiag[r], m * m);
    }
    __syncthreads();
    int n0 = g << GBITS;
    if (t < GSIZE) {
        int n = n0 + t;
        if (n < N) {
            float dm = rdiag[t];
            float ds = rsqrtf(dm + 1.0f);
            dsi[n] = ds;
            diag2[n] = dm * ds * ds;     // full diagonal coefficient
        }
    }
}

// ---------------------------------------------------------------------------
// K6: fused sort+gather per group.  Items staged in LDS, row-sorted in LDS
//     (scalar int atomics only), then 16 half-waves walk row segments.
//     out = x - diag2[n]*y[n,:] + dsi[n] * sum m*mr*dsi[col] * y[col,:]
// ---------------------------------------------------------------------------
__global__ __launch_bounds__(512) void k_gather_fused(
        const ull* __restrict__ binned,
        const int* __restrict__ bhist,
        const int* __restrict__ bsum,
        const unsigned short* __restrict__ y_h,
        const float* __restrict__ x,
        const float* __restrict__ dsi,
        const float* __restrict__ diag2,
        float* __restrict__ out,
        int E, int nblkH, int NBG, int N) {
    __shared__ ull raw[CAP];
    __shared__ ull sorted[CAP];
    __shared__ int rhist[GSIZE];
    __shared__ int rbase[GSIZE];
    __shared__ int cur[GSIZE];
    __shared__ float sds[GSIZE];
    __shared__ float sdg[GSIZE];
    __shared__ int ss[GSIZE];
    __shared__ int sgs[2];
    int g = blockIdx.x, t = threadIdx.x;
    int n0 = g << GBITS;
    if (t < GSIZE) {
        rhist[t] = 0;
        int n = n0 + t;
        if (n < N) { sds[t] = dsi[n]; sdg[t] = diag2[n]; }
    }
    if (t < 2) {
        int gg = g + t;
        if (gg < NBG) {
            int idx = gg * nblkH;
            sgs[t] = bhist[idx] + bsum[idx >> 8];
        } else sgs[t] = E;
    }
    __syncthreads();
    int gstart = sgs[0];
    int cnt = min(sgs[1] - gstart, CAP);

    // load items to LDS + row histogram (1 scalar atomic per item)
    for (int k = t; k < cnt; k += 512) {
        ull it = binned[gstart + k];
        raw[k] = it;
        atomicAdd(&rhist[(int)(it >> 48) & (GSIZE - 1)], 1);
    }
    __syncthreads();

    // exclusive scan of rhist (64 entries; barriers hit by all 512 threads)
    int v = (t < GSIZE) ? rhist[t] : 0;
    if (t < GSIZE) ss[t] = v;
    __syncthreads();
#pragma unroll
    for (int o = 1; o < GSIZE; o <<= 1) {
        int tmp = 0;
        if (t < GSIZE && t >= o) tmp = ss[t - o];
        __syncthreads();
        if (t < GSIZE) ss[t] += tmp;
        __syncthreads();
    }
    if (t < GSIZE) {
        int ex = ss[t] - v;
        rbase[t] = ex;
        cur[t] = ex;
    }
    __syncthreads();

    // counting-scatter to row-sorted LDS order (1 scalar atomic per item)
    for (int k = t; k < cnt; k += 512) {
        ull it = raw[k];
        int r = (int)(it >> 48) & (GSIZE - 1);
        int pos = atomicAdd(&cur[r], 1);
        sorted[pos] = it;
    }
    __syncthreads();

    // walk: 16 half-waves, each owns rows hw, hw+16, ...; lane = dim
    int hw = t >> 5;
    int lane = t & 31;
    int rows = min(GSIZE, N - n0);
    for (int r = hw; r < rows; r += 16) {
        int beg = rbase[r];
        int end_ = beg + rhist[r];
        float acc = 0.f;
        int k = beg;
        for (; k + 4 <= end_; k += 4) {
            ull i0 = sorted[k + 0];
            ull i1 = sorted[k + 1];
            ull i2 = sorted[k + 2];
            ull i3 = sorted[k + 3];
            int c0 = (int)((i0 >> 32) & 0xFFFF);
            int c1 = (int)((i1 >> 32) & 0xFFFF);
            int c2 = (int)((i2 >> 32) & 0xFFFF);
            int c3 = (int)((i3 >> 32) & 0xFFFF);
            float w0 = h2f((unsigned short)((i0 >> 16) & 0xFFFF)) * h2f((unsigned short)(i0 & 0xFFFF)) * dsi[c0];
            float w1 = h2f((unsigned short)((i1 >> 16) & 0xFFFF)) * h2f((unsigned short)(i1 & 0xFFFF)) * dsi[c1];
            float w2 = h2f((unsigned short)((i2 >> 16) & 0xFFFF)) * h2f((unsigned short)(i2 & 0xFFFF)) * dsi[c2];
            float w3 = h2f((unsigned short)((i3 >> 16) & 0xFFFF)) * h2f((unsigned short)(i3 & 0xFFFF)) * dsi[c3];
            acc += w0 * h2f(y_h[(size_t)c0 * D + lane]);
            acc += w1 * h2f(y_h[(size_t)c1 * D + lane]);
            acc += w2 * h2f(y_h[(size_t)c2 * D + lane]);
            acc += w3 * h2f(y_h[(size_t)c3 * D + lane]);
        }
        for (; k < end_; ++k) {
            ull it = sorted[k];
            int c = (int)((it >> 32) & 0xFFFF);
            acc += h2f((unsigned short)((it >> 16) & 0xFFFF)) * h2f((unsigned short)(it & 0xFFFF)) *
                   dsi[c] * h2f(y_h[(size_t)c * D + lane]);
        }
        size_t p = (size_t)(n0 + r) * D + lane;
        float yown = h2f(y_h[p]);
        out[p] = x[p] - sdg[r] * yown + sds[r] * acc;
    }
}

extern "C" void kernel_launch(void* const* d_in, const int* in_sizes, int n_in,
                              void* d_out, int out_size, void* d_ws, size_t ws_size,
                              hipStream_t stream) {
    const float* x      = (const float*)d_in[0];
    const float* sheafW = (const float*)d_in[1];
    const float* linW   = (const float*)d_in[2];
    const float* linb   = (const float*)d_in[3];
    const int*   ei     = (const int*)d_in[4];

    int N  = in_sizes[0] / D;
    int E  = in_sizes[4] / 2;
    int E2 = E / 2;

    int NBG   = (N + GSIZE - 1) >> GBITS;          // 782
    int nblkH = (E2 + PPC - 1) / PPC;              // 196
    int MH    = NBG * nblkH;                       // ~153K
    int nblkA = (MH + 255) / 256;                  // ~599

    // Workspace (8B aligned first):
    // binned[E] u64 | ab[N] float2 | dsi[N] | diag2[N] | y_h[N*D] u16 |
    // bhist[MH] | bsumA[nblkA]
    char* wp = (char*)d_ws;
    ull*    binned = (ull*)wp;    wp += (size_t)E * 8;
    float2* ab     = (float2*)wp; wp += (size_t)N * 8;
    float*  dsi    = (float*)wp;  wp += (size_t)N * 4;
    float*  diag2  = (float*)wp;  wp += (size_t)N * 4;
    unsigned short* y_h = (unsigned short*)wp; wp += (size_t)N * D * 2;
    int*    bhist  = (int*)wp;    wp += (size_t)MH * 4;
    int*    bsumA  = (int*)wp;    wp += (size_t)nblkA * 4;

    float* out = (float*)d_out;

    int nbN = (N + BLK - 1) / BLK;                 // 196

    k_pre_hist<<<nbN + nblkH, BLK, 0, stream>>>(x, sheafW, linW, linb, ei, ab, y_h,
                                                bhist, N, E2, E, nbN, nblkH, NBG);
    k_scanA<<<nblkA, 256, 0, stream>>>(bhist, bsumA, MH);
    k_scanB<<<1, 1024, 0, stream>>>(bsumA, nblkA);
    k_scatter<<<nblkH, BLK, 0, stream>>>(ei, ab, bhist, bsumA, binned, E2, E, nblkH, NBG);
    k_diag<<<NBG, BLK, 0, stream>>>(binned, bhist, bsumA, dsi, diag2, E, nblkH, NBG, N);
    k_gather_fused<<<NBG, 512, 0, stream>>>(binned, bhist, bsumA, y_h, x, dsi, diag2,
                                            out, E, nblkH, NBG, N);
}

// Round 10
// 91.366 us; speedup vs baseline: 4.6744x; 1.1169x over previous
//
#include <hip/hip_runtime.h>

#define D 32
#define GBITS 6
#define GSIZE 64               // rows per group
#define BLK 256
#define PPC 4096               // pairs per hist/scatter chunk
#define IPT 16                 // PPC / BLK
#define CAP 2560               // LDS item capacity per group (mean 2048, ~11 sigma)

typedef unsigned long long ull;

static __device__ __forceinline__ unsigned short f2h(float f) {
    _Float16 h = (_Float16)f;
    return __builtin_bit_cast(unsigned short, h);
}
static __device__ __forceinline__ float h2f(unsigned short u) {
    return (float)__builtin_bit_cast(_Float16, u);
}
static __device__ __forceinline__ float ftanh(float u) {
    u = fminf(fmaxf(u, -15.f), 15.f);
    float e = __expf(2.f * u);
    return (e - 1.f) / (e + 1.f);
}

// ---------------------------------------------------------------------------
// K1 (fused): blocks [0,nbN) per-node precompute (ab + f16 y_h);
//             blocks [nbN,...) blocked bin histogram (bin = row >> GBITS).
// ---------------------------------------------------------------------------
__global__ void k_pre_hist(const float* __restrict__ x,
                           const float* __restrict__ sheafW,
                           const float* __restrict__ linW,
                           const float* __restrict__ linb,
                           const int* __restrict__ ei,
                           float2* __restrict__ ab,
                           unsigned short* __restrict__ y_h,
                           int* __restrict__ bhist,
                           int N, int E2, int E, int nbN, int nblkH, int NBG) {
    if (blockIdx.x < nbN) {
        __shared__ float sW[D * D];
        __shared__ float sB[D];
        __shared__ float sS[2 * D];
        for (int i = threadIdx.x; i < D * D; i += blockDim.x) sW[i] = linW[i];
        if (threadIdx.x < D) sB[threadIdx.x] = linb[threadIdx.x];
        if (threadIdx.x < 2 * D) sS[threadIdx.x] = sheafW[threadIdx.x];
        __syncthreads();

        int n = blockIdx.x * blockDim.x + threadIdx.x;
        if (n >= N) return;

        float xv[D];
        const float4* xp = reinterpret_cast<const float4*>(x + (size_t)n * D);
#pragma unroll
        for (int i = 0; i < D / 4; ++i) {
            float4 v = xp[i];
            xv[4 * i + 0] = v.x; xv[4 * i + 1] = v.y;
            xv[4 * i + 2] = v.z; xv[4 * i + 3] = v.w;
        }

        float av = 0.f, bv = 0.f;
#pragma unroll
        for (int d = 0; d < D; ++d) { av += xv[d] * sS[d]; bv += xv[d] * sS[D + d]; }
        ab[n] = make_float2(av, bv);

        unsigned short yh[D];
#pragma unroll
        for (int j = 0; j < D; ++j) {
            float s = sB[j];
#pragma unroll
            for (int d = 0; d < D; ++d) s += xv[d] * sW[j * D + d];
            yh[j] = f2h(s);
        }
        uint4* dst = reinterpret_cast<uint4*>(y_h + (size_t)n * D);
        const uint4* src = reinterpret_cast<const uint4*>(yh);
#pragma unroll
        for (int q = 0; q < D / 8; ++q) dst[q] = src[q];
    } else {
        __shared__ int hist[1024];
        int blk = blockIdx.x - nbN;
        for (int i = threadIdx.x; i < NBG; i += BLK) hist[i] = 0;
        __syncthreads();
        int base = blk * PPC;
#pragma unroll
        for (int k = 0; k < IPT; ++k) {
            int i = base + k * BLK + threadIdx.x;
            if (i < E2) {
                int s = ei[i];
                int t = ei[E + i];
                atomicAdd(&hist[s >> GBITS], 1);
                atomicAdd(&hist[t >> GBITS], 1);
            }
        }
        __syncthreads();
        for (int i = threadIdx.x; i < NBG; i += BLK)
            bhist[(size_t)i * nblkH + blk] = hist[i];
    }
}

// ---------------------------------------------------------------------------
// Scan level A: 256-elem blocks, local exclusive in place + block sums.
// ---------------------------------------------------------------------------
__global__ void k_scanA(int* __restrict__ data, int* __restrict__ bsum, int M) {
    __shared__ int s[256];
    int t = threadIdx.x;
    int i = blockIdx.x * 256 + t;
    int v = (i < M) ? data[i] : 0;
    s[t] = v;
    __syncthreads();
#pragma unroll
    for (int o = 1; o < 256; o <<= 1) {
        int tmp = (t >= o) ? s[t - o] : 0;
        __syncthreads();
        s[t] += tmp;
        __syncthreads();
    }
    if (i < M) data[i] = s[t] - v;
    if (t == 255) bsum[blockIdx.x] = s[255];
}

// ---------------------------------------------------------------------------
// Scan level B: one 1024-thread block, in-place exclusive scan of NB elems.
// ---------------------------------------------------------------------------
__global__ void k_scanB(int* __restrict__ data, int NB) {
    __shared__ int s[1024];
    int t = threadIdx.x;
    int per = (NB + 1023) >> 10;
    int beg = t * per;
    int end_ = min(beg + per, NB);
    int sum = 0;
    for (int i = beg; i < end_; ++i) sum += data[i];
    s[t] = sum;
    __syncthreads();
#pragma unroll
    for (int o = 1; o < 1024; o <<= 1) {
        int tmp = (t >= o) ? s[t - o] : 0;
        __syncthreads();
        s[t] += tmp;
        __syncthreads();
    }
    int run = s[t] - sum;
    for (int i = beg; i < end_; ++i) { int v = data[i]; data[i] = run; run += v; }
}

// ---------------------------------------------------------------------------
// K4: scatter — recomputes maps from ab, packs (row<<48|col<<32|m16|mr16),
//     writes directly into bin-grouped order via LDS cursors.
// ---------------------------------------------------------------------------
__global__ void k_scatter(const int* __restrict__ ei,
                          const float2* __restrict__ ab,
                          const int* __restrict__ bhist,
                          const int* __restrict__ bsum,
                          ull* __restrict__ binned,
                          int E2, int E, int nblkH, int NBG) {
    __shared__ int cursor[1024];
    for (int i = threadIdx.x; i < NBG; i += BLK) {
        int idx = i * nblkH + blockIdx.x;
        cursor[i] = bhist[idx] + bsum[idx >> 8];
    }
    __syncthreads();
    int base = blockIdx.x * PPC;
#pragma unroll
    for (int k = 0; k < IPT; ++k) {
        int i = base + k * BLK + threadIdx.x;
        if (i < E2) {
            int s = ei[i];
            int t = ei[E + i];
            float2 as = ab[s], at = ab[t];
            float m  = ftanh(as.x + at.y);
            float mr = ftanh(at.x + as.y);
            ull hm = f2h(m), hmr = f2h(mr);
            int pos = atomicAdd(&cursor[s >> GBITS], 1);
            binned[pos] = ((ull)(unsigned)s << 48) | ((ull)(unsigned)t << 32) | (hm << 16) | hmr;
            int pos2 = atomicAdd(&cursor[t >> GBITS], 1);
            binned[pos2] = ((ull)(unsigned)t << 48) | ((ull)(unsigned)s << 32) | (hmr << 16) | hm;
        }
    }
}

// ---------------------------------------------------------------------------
// K5: per-group diag (scalar LDS f32 atomics, 1/item) -> dsi, diag2 (=dm*ds^2).
// ---------------------------------------------------------------------------
__global__ void k_diag(const ull* __restrict__ binned,
                       const int* __restrict__ bhist,
                       const int* __restrict__ bsum,
                       float* __restrict__ dsi, float* __restrict__ diag2,
                       int E, int nblkH, int NBG, int N) {
    __shared__ float rdiag[GSIZE];
    __shared__ int sgs[2];
    int g = blockIdx.x, t = threadIdx.x;
    if (t < GSIZE) rdiag[t] = 0.f;
    if (t < 2) {
        int gg = g + t;
        if (gg < NBG) {
            int idx = gg * nblkH;
            sgs[t] = bhist[idx] + bsum[idx >> 8];
        } else sgs[t] = E;
    }
    __syncthreads();
    int gstart = sgs[0], gend = sgs[1];
    for (int k = gstart + t; k < gend; k += BLK) {
        ull it = binned[k];
        int r = (int)(it >> 48) & (GSIZE - 1);
        float m = h2f((unsigned short)((it >> 16) & 0xFFFF));
        atomicAdd(&rdiag[r], m * m);
    }
    __syncthreads();
    int n0 = g << GBITS;
    if (t < GSIZE) {
        int n = n0 + t;
        if (n < N) {
            float dm = rdiag[t];
            float ds = rsqrtf(dm + 1.0f);
            dsi[n] = ds;
            diag2[n] = dm * ds * ds;     // full diagonal coefficient
        }
    }
}

// ---------------------------------------------------------------------------
// K6: fused sort+gather per group.  No raw staging (binned read twice — 2nd
//     hit is L2-hot); sorted entries are packed u32 (col16 | f16(m*mr*dsi[col]))
//     so the walk is a 4B LDS broadcast + one y_h gather + one fma per item.
//     out = x - diag2[n]*y[n,:] + dsi[n] * sum w * y[col,:]
// ---------------------------------------------------------------------------
__global__ __launch_bounds__(512) void k_gather_fused(
        const ull* __restrict__ binned,
        const int* __restrict__ bhist,
        const int* __restrict__ bsum,
        const unsigned short* __restrict__ y_h,
        const float* __restrict__ x,
        const float* __restrict__ dsi,
        const float* __restrict__ diag2,
        float* __restrict__ out,
        int E, int nblkH, int NBG, int N) {
    __shared__ unsigned int sortedw[CAP];      // 10 KB
    __shared__ int rhist[GSIZE];
    __shared__ int rbase[GSIZE];
    __shared__ int cur[GSIZE];
    __shared__ float sds[GSIZE];
    __shared__ float sdg[GSIZE];
    __shared__ int ss[GSIZE];
    __shared__ int sgs[2];
    int g = blockIdx.x, t = threadIdx.x;
    int n0 = g << GBITS;
    if (t < GSIZE) {
        rhist[t] = 0;
        int n = n0 + t;
        if (n < N) { sds[t] = dsi[n]; sdg[t] = diag2[n]; }
    }
    if (t < 2) {
        int gg = g + t;
        if (gg < NBG) {
            int idx = gg * nblkH;
            sgs[t] = bhist[idx] + bsum[idx >> 8];
        } else sgs[t] = E;
    }
    __syncthreads();
    int gstart = sgs[0];
    int cnt = min(sgs[1] - gstart, CAP);

    // pass 1: row histogram (1 scalar LDS atomic per item)
    for (int k = t; k < cnt; k += 512) {
        ull it = binned[gstart + k];
        atomicAdd(&rhist[(int)(it >> 48) & (GSIZE - 1)], 1);
    }
    __syncthreads();

    // exclusive scan of rhist (64 entries; barriers hit by all 512 threads)
    int v = (t < GSIZE) ? rhist[t] : 0;
    if (t < GSIZE) ss[t] = v;
    __syncthreads();
#pragma unroll
    for (int o = 1; o < GSIZE; o <<= 1) {
        int tmp = 0;
        if (t < GSIZE && t >= o) tmp = ss[t - o];
        __syncthreads();
        if (t < GSIZE) ss[t] += tmp;
        __syncthreads();
    }
    if (t < GSIZE) {
        int ex = ss[t] - v;
        rbase[t] = ex;
        cur[t] = ex;
    }
    __syncthreads();

    // pass 2: re-read binned (L2-hot), fold dsi[col], counting-scatter to
    // row-sorted LDS order (1 scalar atomic + 4B LDS write per item)
    for (int k = t; k < cnt; k += 512) {
        ull it = binned[gstart + k];
        int r = (int)(it >> 48) & (GSIZE - 1);
        unsigned int c = (unsigned int)((it >> 32) & 0xFFFF);
        float w = h2f((unsigned short)((it >> 16) & 0xFFFF)) *
                  h2f((unsigned short)(it & 0xFFFF)) * dsi[c];
        int pos = atomicAdd(&cur[r], 1);
        sortedw[pos] = (c << 16) | (unsigned int)f2h(w);
    }
    __syncthreads();

    // walk: 16 half-waves, each owns rows hw, hw+16, ...; lane = dim
    int hw = t >> 5;
    int lane = t & 31;
    int rows = min(GSIZE, N - n0);
    for (int r = hw; r < rows; r += 16) {
        int beg = rbase[r];
        int end_ = beg + rhist[r];
        float acc = 0.f;
        int k = beg;
        for (; k + 4 <= end_; k += 4) {
            unsigned int e0 = sortedw[k + 0];
            unsigned int e1 = sortedw[k + 1];
            unsigned int e2 = sortedw[k + 2];
            unsigned int e3 = sortedw[k + 3];
            float v0 = h2f(y_h[(size_t)(e0 >> 16) * D + lane]);
            float v1 = h2f(y_h[(size_t)(e1 >> 16) * D + lane]);
            float v2 = h2f(y_h[(size_t)(e2 >> 16) * D + lane]);
            float v3 = h2f(y_h[(size_t)(e3 >> 16) * D + lane]);
            acc += h2f((unsigned short)(e0 & 0xFFFF)) * v0;
            acc += h2f((unsigned short)(e1 & 0xFFFF)) * v1;
            acc += h2f((unsigned short)(e2 & 0xFFFF)) * v2;
            acc += h2f((unsigned short)(e3 & 0xFFFF)) * v3;
        }
        for (; k < end_; ++k) {
            unsigned int e = sortedw[k];
            acc += h2f((unsigned short)(e & 0xFFFF)) *
                   h2f(y_h[(size_t)(e >> 16) * D + lane]);
        }
        size_t p = (size_t)(n0 + r) * D + lane;
        float yown = h2f(y_h[p]);
        out[p] = x[p] - sdg[r] * yown + sds[r] * acc;
    }
}

extern "C" void kernel_launch(void* const* d_in, const int* in_sizes, int n_in,
                              void* d_out, int out_size, void* d_ws, size_t ws_size,
                              hipStream_t stream) {
    const float* x      = (const float*)d_in[0];
    const float* sheafW = (const float*)d_in[1];
    const float* linW   = (const float*)d_in[2];
    const float* linb   = (const float*)d_in[3];
    const int*   ei     = (const int*)d_in[4];

    int N  = in_sizes[0] / D;
    int E  = in_sizes[4] / 2;
    int E2 = E / 2;

    int NBG   = (N + GSIZE - 1) >> GBITS;          // 782
    int nblkH = (E2 + PPC - 1) / PPC;              // 196
    int MH    = NBG * nblkH;                       // ~153K
    int nblkA = (MH + 255) / 256;                  // ~599

    // Workspace (8B aligned first):
    // binned[E] u64 | ab[N] float2 | dsi[N] | diag2[N] | y_h[N*D] u16 |
    // bhist[MH] | bsumA[nblkA]
    char* wp = (char*)d_ws;
    ull*    binned = (ull*)wp;    wp += (size_t)E * 8;
    float2* ab     = (float2*)wp; wp += (size_t)N * 8;
    float*  dsi    = (float*)wp;  wp += (size_t)N * 4;
    float*  diag2  = (float*)wp;  wp += (size_t)N * 4;
    unsigned short* y_h = (unsigned short*)wp; wp += (size_t)N * D * 2;
    int*    bhist  = (int*)wp;    wp += (size_t)MH * 4;
    int*    bsumA  = (int*)wp;    wp += (size_t)nblkA * 4;

    float* out = (float*)d_out;

    int nbN = (N + BLK - 1) / BLK;                 // 196

    k_pre_hist<<<nbN + nblkH, BLK, 0, stream>>>(x, sheafW, linW, linb, ei, ab, y_h,
                                                bhist, N, E2, E, nbN, nblkH, NBG);
    k_scanA<<<nblkA, 256, 0, stream>>>(bhist, bsumA, MH);
    k_scanB<<<1, 1024, 0, stream>>>(bsumA, nblkA);
    k_scatter<<<nblkH, BLK, 0, stream>>>(ei, ab, bhist, bsumA, binned, E2, E, nblkH, NBG);
    k_diag<<<NBG, BLK, 0, stream>>>(binned, bhist, bsumA, dsi, diag2, E, nblkH, NBG, N);
    k_gather_fused<<<NBG, 512, 0, stream>>>(binned, bhist, bsumA, y_h, x, dsi, diag2,
                                            out, E, nblkH, NBG, N);
}